// Round 2
// baseline (30926.059 us; speedup 1.0000x reference)
//
#include <hip/hip_runtime.h>
#include <cstdint>
#include <cstddef>

#define T_LEN 512
#define NTAG  7

// agent-scope (device) atomic helpers: cross-XCD-coherent h exchange
__device__ __forceinline__ float2 aload_f2(const float* p) {
    unsigned long long u = __hip_atomic_load((unsigned long long*)p,
        __ATOMIC_RELAXED, __HIP_MEMORY_SCOPE_AGENT);
    float2 r; __builtin_memcpy(&r, &u, 8); return r;
}
__device__ __forceinline__ void astore_f(float* p, float v) {
    __hip_atomic_store(p, v, __ATOMIC_RELAXED, __HIP_MEMORY_SCOPE_AGENT);
}

// ---------------------------------------------------------------------------
// Persistent fused kernel: per step t, each block computes for its
// (copy: 16 batches, dir, 8 hidden units) both x_t.W_ih and h_{t-1}.W_hh
// (weights register-resident: 128 floats/thread), LSTM cell update, and
// atomic partial tag logits. Cross-block h exchange via hglob + per-group
// 64-block barrier. group g = blockIdx.x & 7 (one XCD per group if placement
// is round-robin; correct regardless).
// ---------------------------------------------------------------------------
__global__ __launch_bounds__(256, 2) void lstm_fused_kernel(
    const int* __restrict__ sent, const float* __restrict__ emb,
    const float* __restrict__ wif, const float* __restrict__ whf,
    const float* __restrict__ bif, const float* __restrict__ bhf,
    const float* __restrict__ wib, const float* __restrict__ whb,
    const float* __restrict__ bib, const float* __restrict__ bhb,
    const float* __restrict__ wout,
    const float* __restrict__ h0, const float* __restrict__ c0,
    float* __restrict__ hglob,   // [2 parity][8 group][16 b][512]
    float* logits,               // [T][64][7], atomicAdd target
    int* barrier)                // [8 group][32]
{
    __shared__ __align__(16) float h_s[8 * 512];   // 16 KB (half-batch stage)
    __shared__ __align__(16) float x_s[8 * 512];   // 16 KB
    __shared__ float sums[32 * 16];                // [local gate row][batch]
    __shared__ float c_s[128];                     // [bb*8+uu]
    __shared__ float hv_s[128];
    __shared__ float bias_s[32];
    __shared__ float wout_s[56];
    __shared__ int   sidx_s[16];

    const int tid  = threadIdx.x;
    const int beta = blockIdx.x;
    const int g    = beta & 7;          // group id (copy,dir)
    const int ub   = beta >> 3;         // unit-block 0..63
    const int d    = g & 1;
    const int b0   = (g >> 1) << 4;     // first batch of this copy
    const int u0   = ub << 3;           // first hidden unit

    const int jg   = tid >> 4;          // 16 row-groups (rows jg, jg+16)
    const int ksub = tid & 15;          // k-slice of 32
    const int k0   = ksub << 5;

    const float* Wi = d ? wib : wif;
    const float* Wh = d ? whb : whf;
    const int r0 = ((jg >> 3) << 9) + u0 + (jg & 7);            // gates 0,1
    const int r1 = (((jg + 16) >> 3) << 9) + u0 + ((jg + 16) & 7); // gates 2,3

    // register-resident weight slices: [row jg | row jg+16] x 32 k
    float wih[64], whh[64];
    {
        const float* p0 = Wi + ((size_t)r0 << 9) + k0;
        const float* p1 = Wi + ((size_t)r1 << 9) + k0;
        const float* q0 = Wh + ((size_t)r0 << 9) + k0;
        const float* q1 = Wh + ((size_t)r1 << 9) + k0;
#pragma unroll
        for (int i = 0; i < 8; ++i) {
            *(float4*)(wih + 4 * i)      = *(const float4*)(p0 + 4 * i);
            *(float4*)(wih + 32 + 4 * i) = *(const float4*)(p1 + 4 * i);
            *(float4*)(whh + 4 * i)      = *(const float4*)(q0 + 4 * i);
            *(float4*)(whh + 32 + 4 * i) = *(const float4*)(q1 + 4 * i);
        }
    }
    if (tid < 32) {
        int grow = ((tid >> 3) << 9) + u0 + (tid & 7);
        bias_s[tid] = d ? (bib[grow] + bhb[grow]) : (bif[grow] + bhf[grow]);
    }
    if (tid < 56) {
        int tg = tid >> 3, uu = tid & 7;
        wout_s[tid] = wout[(size_t)tg * 1024 + (d << 9) + u0 + uu];
    }
    if (tid < 128) {
        int bb = tid >> 3, uu = tid & 7;
        c_s[tid] = c0[(((size_t)d * 64) + b0 + bb) * 512 + u0 + uu];
    }
    int* cnt = barrier + g * 32;
    int* rel = cnt + 16;

    // swizzled LDS read offsets for this k-slice (2-way max -> free)
    int ph[8];
#pragma unroll
    for (int qq = 0; qq < 8; ++qq)
        ph[qq] = k0 + (((qq ^ (ksub >> 1)) & 7) << 2);

    __syncthreads();

    for (int s = 0; s < T_LEN; ++s) {
        const int t = d ? (T_LEN - 1 - s) : s;
        if (tid < 16) sidx_s[tid] = sent[((b0 + tid) << 9) + t];
        __syncthreads();

        const float* hsrc = (s == 0)
            ? (h0 + (((size_t)d * 64 + b0) << 9))
            : (hglob + ((((size_t)(s & 1)) * 8 + g) << 13));

        for (int half = 0; half < 2; ++half) {
            // stage h(t-1) and x_t for 8 batches
#pragma unroll
            for (int i = 0; i < 4; ++i) {
                int f  = (i << 8) + tid;       // 0..1023
                int bq = f >> 7;               // local batch 0..7
                int q  = f & 127;              // float4 quad in row
                int gb = (half << 3) + bq;     // batch-in-copy 0..15
                float4 xv = *(const float4*)(emb + (((size_t)sidx_s[gb]) << 9) + (q << 2));
                float4 hvv;
                if (s == 0) {
                    hvv = *(const float4*)(hsrc + ((size_t)gb << 9) + (q << 2));
                } else {
                    float2 lo = aload_f2(hsrc + ((size_t)gb << 9) + (q << 2));
                    float2 hi = aload_f2(hsrc + ((size_t)gb << 9) + (q << 2) + 2);
                    hvv = make_float4(lo.x, lo.y, hi.x, hi.y);
                }
                int sq   = ((q >> 3) << 3) | ((q & 7) ^ ((q >> 4) & 7));
                int lofs = (bq << 9) + (sq << 2);
                *(float4*)(h_s + lofs) = hvv;
                *(float4*)(x_s + lofs) = xv;
            }
            __syncthreads();

            for (int bl = 0; bl < 8; ++bl) {
                const int b = (half << 3) + bl;
                const float* hb = h_s + (bl << 9);
                const float* xb = x_s + (bl << 9);
                float acc0 = 0.f, acc1 = 0.f;
#pragma unroll
                for (int qq = 0; qq < 8; ++qq) {
                    float4 hv = *(const float4*)(hb + ph[qq]);
                    float4 xv = *(const float4*)(xb + ph[qq]);
                    acc0 = fmaf(hv.x, whh[4 * qq + 0], acc0);
                    acc0 = fmaf(hv.y, whh[4 * qq + 1], acc0);
                    acc0 = fmaf(hv.z, whh[4 * qq + 2], acc0);
                    acc0 = fmaf(hv.w, whh[4 * qq + 3], acc0);
                    acc0 = fmaf(xv.x, wih[4 * qq + 0], acc0);
                    acc0 = fmaf(xv.y, wih[4 * qq + 1], acc0);
                    acc0 = fmaf(xv.z, wih[4 * qq + 2], acc0);
                    acc0 = fmaf(xv.w, wih[4 * qq + 3], acc0);
                    acc1 = fmaf(hv.x, whh[32 + 4 * qq + 0], acc1);
                    acc1 = fmaf(hv.y, whh[32 + 4 * qq + 1], acc1);
                    acc1 = fmaf(hv.z, whh[32 + 4 * qq + 2], acc1);
                    acc1 = fmaf(hv.w, whh[32 + 4 * qq + 3], acc1);
                    acc1 = fmaf(xv.x, wih[32 + 4 * qq + 0], acc1);
                    acc1 = fmaf(xv.y, wih[32 + 4 * qq + 1], acc1);
                    acc1 = fmaf(xv.z, wih[32 + 4 * qq + 2], acc1);
                    acc1 = fmaf(xv.w, wih[32 + 4 * qq + 3], acc1);
                }
#pragma unroll
                for (int m = 8; m; m >>= 1) {
                    acc0 += __shfl_xor(acc0, m);
                    acc1 += __shfl_xor(acc1, m);
                }
                if (ksub == 0) {
                    sums[(jg << 4) | b]        = acc0;
                    sums[((jg + 16) << 4) | b] = acc1;
                }
            }
            __syncthreads();
        }

        // LSTM cell update (one lane per (batch,unit))
        if (tid < 128) {
            const int bb = tid >> 3, uu = tid & 7;
            float si = sums[((uu)      << 4) | bb] + bias_s[uu];
            float sf = sums[((8 + uu)  << 4) | bb] + bias_s[8 + uu];
            float sg = sums[((16 + uu) << 4) | bb] + bias_s[16 + uu];
            float so = sums[((24 + uu) << 4) | bb] + bias_s[24 + uu];
            float ig = 1.f / (1.f + expf(-si));
            float fg = 1.f / (1.f + expf(-sf));
            float gv = tanhf(sg);
            float og = 1.f / (1.f + expf(-so));
            float cn = fg * c_s[tid] + ig * gv;
            c_s[tid] = cn;
            float hh = og * tanhf(cn);
            hv_s[tid] = hh;
            astore_f(hglob + ((((size_t)((s + 1) & 1)) * 8 + g) << 13)
                           + ((size_t)bb << 9) + u0 + uu, hh);
        }
        __syncthreads();

        // partial tag logits for this block's 8 units
        if (tid < 112) {
            const int tg = tid >> 4, bb = tid & 15;
            float a = 0.f;
#pragma unroll
            for (int uu = 0; uu < 8; ++uu)
                a = fmaf(hv_s[(bb << 3) | uu], wout_s[(tg << 3) | uu], a);
            atomicAdd(logits + ((size_t)t * 64 + b0 + bb) * NTAG + tg, a);
        }

        // 64-block group barrier (monotonic count + release flag)
        __threadfence();
        __syncthreads();
        if (tid == 0) {
            int old = __hip_atomic_fetch_add(cnt, 1, __ATOMIC_ACQ_REL,
                                             __HIP_MEMORY_SCOPE_AGENT);
            if (old == ((s + 1) << 6) - 1) {
                __hip_atomic_store(rel, s + 1, __ATOMIC_RELEASE,
                                   __HIP_MEMORY_SCOPE_AGENT);
            } else {
                while (__hip_atomic_load(rel, __ATOMIC_ACQUIRE,
                                         __HIP_MEMORY_SCOPE_AGENT) < s + 1)
                    __builtin_amdgcn_s_sleep(1);
            }
        }
        __syncthreads();
    }
}

// ---------------------------------------------------------------------------
// Viterbi decode: one wave per batch (lanes 0..6 = tags), byte backpointers,
// shuffle backtrace. Adds b_out at load.
// ---------------------------------------------------------------------------
__global__ __launch_bounds__(256) void viterbi_kernel(
    const float* __restrict__ logits, const float* __restrict__ bout,
    const float* __restrict__ trans,
    unsigned char* __restrict__ bp,   // [64][512][8]
    float* __restrict__ out)          // [64 scores][64*512 paths]
{
    __shared__ float Ls[4][512][7];   // 56 KB
    const int tid = threadIdx.x;
    const int b0 = blockIdx.x << 2;

    for (int idx = tid; idx < 4 * 512 * 7; idx += 256) {
        int bl = idx / 3584;
        int rem = idx - bl * 3584;
        int t = rem / 7;
        int tg = rem - t * 7;
        Ls[bl][t][tg] = logits[((size_t)t * 64 + b0 + bl) * 7 + tg] + bout[tg];
    }
    __syncthreads();

    const int w = tid >> 6;
    const int lane = tid & 63;
    const int b = b0 + w;
    const int k = lane;

    float tr[7];
#pragma unroll
    for (int j = 0; j < 7; ++j) tr[j] = (k < 7) ? trans[j * 7 + k] : -1e30f;
    float prev = (k < 7) ? Ls[w][0][k] : -1e30f;
    unsigned char* bpb = bp + (size_t)b * 512 * 8;

    for (int t = 1; t < 512; ++t) {
        float best = __shfl(prev, 0, 64) + tr[0];
        int bj = 0;
#pragma unroll
        for (int j = 1; j < 7; ++j) {
            float v = __shfl(prev, j, 64) + tr[j];
            if (v > best) { best = v; bj = j; }   // strict > = first argmax
        }
        float lv = (k < 7) ? Ls[w][t][k] : 0.f;
        if (k < 7) bpb[t * 8 + k] = (unsigned char)bj;
        prev = lv + best;
    }

    float pv[7];
#pragma unroll
    for (int j = 0; j < 7; ++j) pv[j] = __shfl(prev, j, 64);
    float best = pv[0]; int bj = 0;
#pragma unroll
    for (int j = 1; j < 7; ++j) if (pv[j] > best) { best = pv[j]; bj = j; }
    if (lane == 0) {
        out[b] = best;
        out[64 + (size_t)b * 512 + 511] = (float)bj;
    }

    int cur = bj;
    for (int tc = 448; tc >= 0; tc -= 64) {
        int t = tc + lane;
        unsigned long long row = *(const unsigned long long*)(bpb + (size_t)t * 8);
        for (int i = 63; i >= 0; --i) {
            int t2 = tc + i;
            if (t2 < 1) break;
            unsigned long long r = __shfl(row, i, 64);
            cur = (int)((r >> (cur * 8)) & 0xFF);
            if (lane == 0) out[64 + (size_t)b * 512 + (t2 - 1)] = (float)cur;
        }
    }
}

// ---------------------------------------------------------------------------
extern "C" void kernel_launch(void* const* d_in, const int* in_sizes, int n_in,
                              void* d_out, int out_size, void* d_ws, size_t ws_size,
                              hipStream_t stream)
{
    (void)in_sizes; (void)n_in; (void)out_size; (void)ws_size;
    const int*   sent = (const int*)d_in[0];
    const float* emb  = (const float*)d_in[1];
    const float* wif  = (const float*)d_in[2];
    const float* whf  = (const float*)d_in[3];
    const float* bif  = (const float*)d_in[4];
    const float* bhf  = (const float*)d_in[5];
    const float* wib  = (const float*)d_in[6];
    const float* whb  = (const float*)d_in[7];
    const float* bib  = (const float*)d_in[8];
    const float* bhb  = (const float*)d_in[9];
    const float* wout = (const float*)d_in[10];
    const float* bout = (const float*)d_in[11];
    const float* h0   = (const float*)d_in[12];
    const float* c0   = (const float*)d_in[13];
    const float* trans= (const float*)d_in[14];
    float* out = (float*)d_out;

    // workspace layout (total ~1.7 MB)
    float* logits = (float*)d_ws;                          // 229376 f
    int*   barrier = (int*)(logits + 229376);              // 256 int
    float* hglob  = (float*)(barrier + 256);               // 131072 f
    unsigned char* bp = (unsigned char*)(hglob + 131072);  // 262144 B

    // zero logits + barrier in one contiguous memset
    hipMemsetAsync(d_ws, 0, 229376 * 4 + 256 * 4, stream);

    lstm_fused_kernel<<<512, 256, 0, stream>>>(
        sent, emb, wif, whf, bif, bhf, wib, whb, bib, bhb,
        wout, h0, c0, hglob, logits, barrier);
    viterbi_kernel<<<16, 256, 0, stream>>>(logits, bout, trans, bp, out);
}

// Round 3
// 14828.604 us; speedup vs baseline: 2.0856x; 2.0856x over previous
//
#include <hip/hip_runtime.h>
#include <cstdint>
#include <cstddef>

#define NTAG 7

// Relaxed agent-scope atomics: bypass non-coherent per-XCD L2s (coherence at L3),
// no fences needed. Verified correct in round 2 (absmax 0.0).
__device__ __forceinline__ float2 aload_f2(const float* p) {
    unsigned long long u = __hip_atomic_load((const unsigned long long*)p,
        __ATOMIC_RELAXED, __HIP_MEMORY_SCOPE_AGENT);
    float2 r; __builtin_memcpy(&r, &u, 8); return r;
}
__device__ __forceinline__ void astore_f(float* p, float v) {
    __hip_atomic_store(p, v, __ATOMIC_RELAXED, __HIP_MEMORY_SCOPE_AGENT);
}

// ---------------------------------------------------------------------------
// Persistent fused BiLSTM. 512 blocks x 256 thr, 2 blocks/CU (all co-resident).
// group g = blockIdx&7 -> (copy of 16 batches, dir). ub = blockIdx>>3 -> 8 units.
// Per step: [poll h ready] -> stage h (L3 atomic loads) -> (ub<7: logits for
// t(s-1), single writer) -> h-MAC combined with PRE-COMPUTED x-partials ->
// cell -> store h -> arrive -> stage+MAC x for t(s+1) (hidden in barrier wait).
// ---------------------------------------------------------------------------
__global__ __launch_bounds__(256, 2) void lstm_fused_kernel(
    const int* __restrict__ sent, const float* __restrict__ emb,
    const float* __restrict__ wif, const float* __restrict__ whf,
    const float* __restrict__ bif, const float* __restrict__ bhf,
    const float* __restrict__ wib, const float* __restrict__ whb,
    const float* __restrict__ bib, const float* __restrict__ bhb,
    const float* __restrict__ wout,
    const float* __restrict__ h0, const float* __restrict__ c0,
    float* __restrict__ hglob,    // [2 parity][8 g][16 b][512]
    float* __restrict__ logits2,  // [2 dir][512 t][64 b][7]
    int* barrier)                 // [8 g][64]
{
    __shared__ __align__(16) float buf[16 * 512];      // shared h/x stage, 32 KB
    __shared__ __align__(16) float wout_row_s[512];    // swizzled like buf
    __shared__ float sums[32 * 16];
    __shared__ float c_s[128];
    __shared__ float bias_s[32];
    __shared__ int   sidx_s[16];

    const int tid = threadIdx.x;
    const int g   = blockIdx.x & 7;
    const int ub  = blockIdx.x >> 3;
    const int d   = g & 1;
    const int b0  = (g >> 1) << 4;
    const int u0  = ub << 3;

    const int jg   = tid >> 4;    // 16 row-groups: local rows jg, jg+16
    const int ksub = tid & 15;    // k-slice of 32
    const int k0   = ksub << 5;

    const float* Wi = d ? wib : wif;
    const float* Wh = d ? whb : whf;
    const int r0 = ((jg >> 3) << 9) + u0 + (jg & 7);
    const int r1 = (((jg + 16) >> 3) << 9) + u0 + ((jg + 16) & 7);

    float wih[64], whh[64];
    {
        const float* p0 = Wi + ((size_t)r0 << 9) + k0;
        const float* p1 = Wi + ((size_t)r1 << 9) + k0;
        const float* q0 = Wh + ((size_t)r0 << 9) + k0;
        const float* q1 = Wh + ((size_t)r1 << 9) + k0;
#pragma unroll
        for (int i = 0; i < 8; ++i) {
            *(float4*)(wih + 4 * i)      = *(const float4*)(p0 + 4 * i);
            *(float4*)(wih + 32 + 4 * i) = *(const float4*)(p1 + 4 * i);
            *(float4*)(whh + 4 * i)      = *(const float4*)(q0 + 4 * i);
            *(float4*)(whh + 32 + 4 * i) = *(const float4*)(q1 + 4 * i);
        }
    }
    if (tid < 128) {   // wout row for this block's tag (ub<7), buf-swizzled
        int q = tid;
        int tag = (ub < NTAG) ? ub : 0;
        float4 wv = *(const float4*)(wout + (size_t)tag * 1024 + (d << 9) + (q << 2));
        int sq = ((q >> 3) << 3) | ((q & 7) ^ ((q >> 4) & 7));
        *(float4*)(wout_row_s + (sq << 2)) = wv;
    }
    if (tid < 32) {
        int grow = ((tid >> 3) << 9) + u0 + (tid & 7);
        bias_s[tid] = d ? (bib[grow] + bhb[grow]) : (bif[grow] + bhf[grow]);
    }
    if (tid < 128) {
        int bb = tid >> 3, uu = tid & 7;
        c_s[tid] = c0[(((size_t)d * 64) + b0 + bb) * 512 + u0 + uu];
    }
    if (tid < 16) sidx_s[tid] = sent[((b0 + tid) << 9) + (d ? 511 : 0)];

    int* cnt = barrier + (g << 6);
    int* rel = cnt + 32;     // 128 B apart from cnt

    int ph[8];
#pragma unroll
    for (int qq = 0; qq < 8; ++qq)
        ph[qq] = k0 + (((qq ^ (ksub >> 1)) & 7) << 2);

    __syncthreads();

    // ---- pre-loop: stage x(t(0)) and compute x-partials into registers ----
    float xacc0[16], xacc1[16];
#pragma unroll
    for (int i = 0; i < 8; ++i) {
        int f = (i << 8) + tid;
        int gb = f >> 7, q = f & 127;
        float4 v = *(const float4*)(emb + (((size_t)sidx_s[gb]) << 9) + (q << 2));
        int sq = ((q >> 3) << 3) | ((q & 7) ^ ((q >> 4) & 7));
        *(float4*)(buf + (gb << 9) + (sq << 2)) = v;
    }
    __syncthreads();
#pragma unroll
    for (int b = 0; b < 16; ++b) {
        const float* xb = buf + (b << 9);
        float a0 = 0.f, a1 = 0.f;
#pragma unroll
        for (int qq = 0; qq < 8; ++qq) {
            float4 xv = *(const float4*)(xb + ph[qq]);
            a0 = fmaf(xv.x, wih[4*qq+0], a0); a0 = fmaf(xv.y, wih[4*qq+1], a0);
            a0 = fmaf(xv.z, wih[4*qq+2], a0); a0 = fmaf(xv.w, wih[4*qq+3], a0);
            a1 = fmaf(xv.x, wih[32+4*qq+0], a1); a1 = fmaf(xv.y, wih[32+4*qq+1], a1);
            a1 = fmaf(xv.z, wih[32+4*qq+2], a1); a1 = fmaf(xv.w, wih[32+4*qq+3], a1);
        }
        xacc0[b] = a0; xacc1[b] = a1;
    }

    for (int s = 0; s < 512; ++s) {
        // prefetch next token indices; wait for h(s) availability
        if (s < 511 && tid < 16)
            sidx_s[tid] = sent[((b0 + tid) << 9) + (d ? (510 - s) : (s + 1))];
        if (s > 0 && tid == 0) {
            while (__hip_atomic_load(rel, __ATOMIC_RELAXED,
                                     __HIP_MEMORY_SCOPE_AGENT) < s)
                __builtin_amdgcn_s_sleep(1);
        }
        __syncthreads();

        // ---- stage h_in(s) ----
        if (s == 0) {
            const float* hs0 = h0 + (((size_t)d * 64 + b0) << 9);
#pragma unroll
            for (int i = 0; i < 8; ++i) {
                int f = (i << 8) + tid;
                int gb = f >> 7, q = f & 127;
                float4 v = *(const float4*)(hs0 + ((size_t)gb << 9) + (q << 2));
                int sq = ((q >> 3) << 3) | ((q & 7) ^ ((q >> 4) & 7));
                *(float4*)(buf + (gb << 9) + (sq << 2)) = v;
            }
        } else {
            const float* hp = hglob + ((((size_t)(s & 1)) << 3 | g) << 13);
#pragma unroll
            for (int i = 0; i < 8; ++i) {
                int f = (i << 8) + tid;
                int gb = f >> 7, q = f & 127;
                float2 lo = aload_f2(hp + ((size_t)gb << 9) + (q << 2));
                float2 hi = aload_f2(hp + ((size_t)gb << 9) + (q << 2) + 2);
                float4 v = make_float4(lo.x, lo.y, hi.x, hi.y);
                int sq = ((q >> 3) << 3) | ((q & 7) ^ ((q >> 4) & 7));
                *(float4*)(buf + (gb << 9) + (sq << 2)) = v;
            }
        }
        __syncthreads();

        // ---- logits for previous position from staged h (single writer) ----
        if (ub < NTAG && s > 0) {
            const int t_prev = d ? (512 - s) : (s - 1);
            const int bb = tid >> 4;
            float a = 0.f;
#pragma unroll
            for (int j = 0; j < 8; ++j) {
                float4 hv = *(const float4*)(buf + (bb << 9) + ph[j]);
                float4 wv = *(const float4*)(wout_row_s + ph[j]);
                a = fmaf(hv.x, wv.x, a); a = fmaf(hv.y, wv.y, a);
                a = fmaf(hv.z, wv.z, a); a = fmaf(hv.w, wv.w, a);
            }
#pragma unroll
            for (int m = 8; m; m >>= 1) a += __shfl_xor(a, m);
            if (ksub == 0)
                logits2[(((size_t)d * 512 + t_prev) * 64 + b0 + bb) * NTAG + ub] = a;
        }

        // ---- h-MAC, combined with x-partials ----
#pragma unroll
        for (int b = 0; b < 16; ++b) {
            const float* hb = buf + (b << 9);
            float a0 = xacc0[b], a1 = xacc1[b];
#pragma unroll
            for (int qq = 0; qq < 8; ++qq) {
                float4 hv = *(const float4*)(hb + ph[qq]);
                a0 = fmaf(hv.x, whh[4*qq+0], a0); a0 = fmaf(hv.y, whh[4*qq+1], a0);
                a0 = fmaf(hv.z, whh[4*qq+2], a0); a0 = fmaf(hv.w, whh[4*qq+3], a0);
                a1 = fmaf(hv.x, whh[32+4*qq+0], a1); a1 = fmaf(hv.y, whh[32+4*qq+1], a1);
                a1 = fmaf(hv.z, whh[32+4*qq+2], a1); a1 = fmaf(hv.w, whh[32+4*qq+3], a1);
            }
#pragma unroll
            for (int m = 8; m; m >>= 1) {
                a0 += __shfl_xor(a0, m);
                a1 += __shfl_xor(a1, m);
            }
            if (ksub == 0) {
                sums[(jg << 4) | b]        = a0;
                sums[((jg + 16) << 4) | b] = a1;
            }
        }
        __syncthreads();

        // ---- cell update + h store ----
        if (tid < 128) {
            const int bb = tid >> 3, uu = tid & 7;
            float si = sums[((uu)      << 4) | bb] + bias_s[uu];
            float sf = sums[((8 + uu)  << 4) | bb] + bias_s[8 + uu];
            float sg = sums[((16 + uu) << 4) | bb] + bias_s[16 + uu];
            float so = sums[((24 + uu) << 4) | bb] + bias_s[24 + uu];
            float ig = 1.f / (1.f + expf(-si));
            float fg = 1.f / (1.f + expf(-sf));
            float gv = tanhf(sg);
            float og = 1.f / (1.f + expf(-so));
            float cn = fg * c_s[tid] + ig * gv;
            c_s[tid] = cn;
            float hh = og * tanhf(cn);
            astore_f(hglob + ((((size_t)((s + 1) & 1)) << 3 | g) << 13)
                           + ((size_t)bb << 9) + u0 + uu, hh);
        }
        __builtin_amdgcn_s_waitcnt(0);   // per-wave: h stores at L3 before barrier
        __syncthreads();

        // ---- arrive (non-blocking), then overlap x(t(s+1)) with the wait ----
        if (tid == 0) {
            int old = __hip_atomic_fetch_add(cnt, 1, __ATOMIC_RELAXED,
                                             __HIP_MEMORY_SCOPE_AGENT);
            if (old == (s << 6) + 63)
                __hip_atomic_store(rel, s + 1, __ATOMIC_RELAXED,
                                   __HIP_MEMORY_SCOPE_AGENT);
        }
        if (s < 511) {
#pragma unroll
            for (int i = 0; i < 8; ++i) {
                int f = (i << 8) + tid;
                int gb = f >> 7, q = f & 127;
                float4 v = *(const float4*)(emb + (((size_t)sidx_s[gb]) << 9) + (q << 2));
                int sq = ((q >> 3) << 3) | ((q & 7) ^ ((q >> 4) & 7));
                *(float4*)(buf + (gb << 9) + (sq << 2)) = v;
            }
            __syncthreads();
#pragma unroll
            for (int b = 0; b < 16; ++b) {
                const float* xb = buf + (b << 9);
                float a0 = 0.f, a1 = 0.f;
#pragma unroll
                for (int qq = 0; qq < 8; ++qq) {
                    float4 xv = *(const float4*)(xb + ph[qq]);
                    a0 = fmaf(xv.x, wih[4*qq+0], a0); a0 = fmaf(xv.y, wih[4*qq+1], a0);
                    a0 = fmaf(xv.z, wih[4*qq+2], a0); a0 = fmaf(xv.w, wih[4*qq+3], a0);
                    a1 = fmaf(xv.x, wih[32+4*qq+0], a1); a1 = fmaf(xv.y, wih[32+4*qq+1], a1);
                    a1 = fmaf(xv.z, wih[32+4*qq+2], a1); a1 = fmaf(xv.w, wih[32+4*qq+3], a1);
                }
                xacc0[b] = a0; xacc1[b] = a1;
            }
        }
    }

    // ---- epilogue: logits for final position t(511) ----
    if (ub < NTAG) {
        if (tid == 0) {
            while (__hip_atomic_load(rel, __ATOMIC_RELAXED,
                                     __HIP_MEMORY_SCOPE_AGENT) < 512)
                __builtin_amdgcn_s_sleep(1);
        }
        __syncthreads();
        const float* hp = hglob + (((size_t)g) << 13);   // parity 0
#pragma unroll
        for (int i = 0; i < 8; ++i) {
            int f = (i << 8) + tid;
            int gb = f >> 7, q = f & 127;
            float2 lo = aload_f2(hp + ((size_t)gb << 9) + (q << 2));
            float2 hi = aload_f2(hp + ((size_t)gb << 9) + (q << 2) + 2);
            float4 v = make_float4(lo.x, lo.y, hi.x, hi.y);
            int sq = ((q >> 3) << 3) | ((q & 7) ^ ((q >> 4) & 7));
            *(float4*)(buf + (gb << 9) + (sq << 2)) = v;
        }
        __syncthreads();
        const int t_prev = d ? 0 : 511;
        const int bb = tid >> 4;
        float a = 0.f;
#pragma unroll
        for (int j = 0; j < 8; ++j) {
            float4 hv = *(const float4*)(buf + (bb << 9) + ph[j]);
            float4 wv = *(const float4*)(wout_row_s + ph[j]);
            a = fmaf(hv.x, wv.x, a); a = fmaf(hv.y, wv.y, a);
            a = fmaf(hv.z, wv.z, a); a = fmaf(hv.w, wv.w, a);
        }
#pragma unroll
        for (int m = 8; m; m >>= 1) a += __shfl_xor(a, m);
        if (ksub == 0)
            logits2[(((size_t)d * 512 + t_prev) * 64 + b0 + bb) * NTAG + ub] = a;
    }
}

// ---------------------------------------------------------------------------
// Viterbi decode: one wave per batch (lanes 0..6 = tags), byte backpointers,
// shuffle backtrace. Sums fwd/bwd logits + b_out at load.
// ---------------------------------------------------------------------------
__global__ __launch_bounds__(256) void viterbi_kernel(
    const float* __restrict__ logits2, const float* __restrict__ bout,
    const float* __restrict__ trans,
    unsigned char* __restrict__ bp,   // [64][512][8]
    float* __restrict__ out)          // [64 scores][64*512 paths]
{
    __shared__ float Ls[4][512][7];   // 56 KB
    const int tid = threadIdx.x;
    const int b0 = blockIdx.x << 2;
    const float* lf = logits2;
    const float* lb = logits2 + (size_t)512 * 64 * 7;

    for (int idx = tid; idx < 4 * 512 * 7; idx += 256) {
        int bl = idx / 3584;
        int rem = idx - bl * 3584;
        int t = rem / 7;
        int tg = rem - t * 7;
        size_t o = ((size_t)t * 64 + b0 + bl) * 7 + tg;
        Ls[bl][t][tg] = lf[o] + lb[o] + bout[tg];
    }
    __syncthreads();

    const int w = tid >> 6;
    const int lane = tid & 63;
    const int b = b0 + w;
    const int k = lane;

    float tr[7];
#pragma unroll
    for (int j = 0; j < 7; ++j) tr[j] = (k < 7) ? trans[j * 7 + k] : -1e30f;
    float prev = (k < 7) ? Ls[w][0][k] : -1e30f;
    unsigned char* bpb = bp + (size_t)b * 512 * 8;

    for (int t = 1; t < 512; ++t) {
        float best = __shfl(prev, 0, 64) + tr[0];
        int bj = 0;
#pragma unroll
        for (int j = 1; j < 7; ++j) {
            float v = __shfl(prev, j, 64) + tr[j];
            if (v > best) { best = v; bj = j; }   // strict > = first argmax
        }
        float lv = (k < 7) ? Ls[w][t][k] : 0.f;
        if (k < 7) bpb[t * 8 + k] = (unsigned char)bj;
        prev = lv + best;
    }

    float pv[7];
#pragma unroll
    for (int j = 0; j < 7; ++j) pv[j] = __shfl(prev, j, 64);
    float best = pv[0]; int bj = 0;
#pragma unroll
    for (int j = 1; j < 7; ++j) if (pv[j] > best) { best = pv[j]; bj = j; }
    if (lane == 0) {
        out[b] = best;
        out[64 + (size_t)b * 512 + 511] = (float)bj;
    }

    int cur = bj;
    for (int tc = 448; tc >= 0; tc -= 64) {
        int t = tc + lane;
        unsigned long long row = *(const unsigned long long*)(bpb + (size_t)t * 8);
        for (int i = 63; i >= 0; --i) {
            int t2 = tc + i;
            if (t2 < 1) break;
            unsigned long long r = __shfl(row, i, 64);
            cur = (int)((r >> (cur * 8)) & 0xFF);
            if (lane == 0) out[64 + (size_t)b * 512 + (t2 - 1)] = (float)cur;
        }
    }
}

// ---------------------------------------------------------------------------
extern "C" void kernel_launch(void* const* d_in, const int* in_sizes, int n_in,
                              void* d_out, int out_size, void* d_ws, size_t ws_size,
                              hipStream_t stream)
{
    (void)in_sizes; (void)n_in; (void)out_size; (void)ws_size;
    const int*   sent = (const int*)d_in[0];
    const float* emb  = (const float*)d_in[1];
    const float* wif  = (const float*)d_in[2];
    const float* whf  = (const float*)d_in[3];
    const float* bif  = (const float*)d_in[4];
    const float* bhf  = (const float*)d_in[5];
    const float* wib  = (const float*)d_in[6];
    const float* whb  = (const float*)d_in[7];
    const float* bib  = (const float*)d_in[8];
    const float* bhb  = (const float*)d_in[9];
    const float* wout = (const float*)d_in[10];
    const float* bout = (const float*)d_in[11];
    const float* h0   = (const float*)d_in[12];
    const float* c0   = (const float*)d_in[13];
    const float* trans= (const float*)d_in[14];
    float* out = (float*)d_out;

    // ws layout (~2.6 MB): barrier | logits2 | hglob | bp
    int*   barrier = (int*)d_ws;                            // 512 ints
    float* logits2 = (float*)(barrier + 512);               // 458752 f
    float* hglob   = logits2 + 458752;                      // 131072 f
    unsigned char* bp = (unsigned char*)(hglob + 131072);   // 262144 B

    hipMemsetAsync(barrier, 0, 512 * sizeof(int), stream);

    lstm_fused_kernel<<<512, 256, 0, stream>>>(
        sent, emb, wif, whf, bif, bhf, wib, whb, bib, bhb,
        wout, h0, c0, hglob, logits2, barrier);
    viterbi_kernel<<<16, 256, 0, stream>>>(logits2, bout, trans, bp, out);
}

// Round 4
// 12393.352 us; speedup vs baseline: 2.4954x; 1.1965x over previous
//
#include <hip/hip_runtime.h>
#include <cstdint>
#include <cstddef>

#define NTAG 7

using bf16x8 = __attribute__((ext_vector_type(8))) short;
using f32x4  = __attribute__((ext_vector_type(4))) float;
typedef unsigned int  u32;
typedef unsigned long long u64;

#define MFMA(A,B,C) __builtin_amdgcn_mfma_f32_16x16x32_bf16((A),(B),(C),0,0,0)

union frag_u { u32 d[4]; bf16x8 v; };

// ---------------------------------------------------------------------------
// Prep 1: convert w_ih/w_hh (both dirs) fp32 -> bf16 hi/lo planes.
// planes layout: [(dir*2+mat)*2+plane][2048][512] ushort, mat: 0=ih 1=hh
// split: hi = trunc-bf16(v); lo = trunc-bf16(v - hi)  (total ~16-17 mantissa bits)
// ---------------------------------------------------------------------------
__global__ __launch_bounds__(256) void prep_weights_kernel(
    const float* __restrict__ wif, const float* __restrict__ whf,
    const float* __restrict__ wib, const float* __restrict__ whb,
    ushort* __restrict__ planes)
{
    int f = blockIdx.x * 256 + threadIdx.x;        // 1,048,576 threads, 4 elems each
    int mat = f >> 18;
    int i4  = (f & 0x3FFFF) << 2;
    const float* src = (mat == 0) ? wif : (mat == 1) ? whf : (mat == 2) ? wib : whb;
    float4 v = *(const float4*)(src + i4);
    ushort hi[4], lo[4];
    float* pv = (float*)&v;
#pragma unroll
    for (int j = 0; j < 4; ++j) {
        u32 b = __float_as_uint(pv[j]);
        hi[j] = (ushort)(b >> 16);
        float r = pv[j] - __uint_as_float(b & 0xffff0000u);
        lo[j] = (ushort)(__float_as_uint(r) >> 16);
    }
    int dir = mat >> 1, m = mat & 1;
    ushort* dh = planes + ((size_t)((dir*2 + m)*2 + 0)) * 1048576 + i4;
    ushort* dl = planes + ((size_t)((dir*2 + m)*2 + 1)) * 1048576 + i4;
    *(ushort4*)dh = make_ushort4(hi[0], hi[1], hi[2], hi[3]);
    *(ushort4*)dl = make_ushort4(lo[0], lo[1], lo[2], lo[3]);
}

// ---------------------------------------------------------------------------
// Prep 2 (optional, needs 64 MB ws): gather + split-pack x = emb[sent]
// xpk[b][t][e] = (bf16hi(x)<<16) | bf16lo(x)
// ---------------------------------------------------------------------------
__global__ __launch_bounds__(256) void prep_x_kernel(
    const int* __restrict__ sent, const float* __restrict__ emb,
    u32* __restrict__ xpk)
{
    long f  = (long)blockIdx.x * 256 + threadIdx.x;  // 4,194,304 threads
    long e4 = f << 2;
    int b = (int)(e4 >> 18);
    int t = (int)((e4 >> 9) & 511);
    int e = (int)(e4 & 511);
    int tok = sent[b * 512 + t];
    float4 v = *(const float4*)(emb + (size_t)tok * 512 + e);
    float* pv = (float*)&v;
    u32 pk[4];
#pragma unroll
    for (int j = 0; j < 4; ++j) {
        u32 bb = __float_as_uint(pv[j]);
        float r = pv[j] - __uint_as_float(bb & 0xffff0000u);
        pk[j] = (bb & 0xffff0000u) | (__float_as_uint(r) >> 16);
    }
    *(uint4*)(xpk + e4) = make_uint4(pk[0], pk[1], pk[2], pk[3]);
}

// ---------------------------------------------------------------------------
// Main persistent kernel: 128 blocks x 256 thr (4 waves), 1 block/CU.
// block = (dir d, batch-half bh: 32 b, unit-tile ut: 16 u -> 64 gate-rows).
// wave w: batches bs=(w&1)*16, gate-pair gp=w>>1 -> 2 gates x 16 units = 2 n-tiles.
// W_hh bf16 hi/lo B-frags register-resident (64 x bf16x8 = 256 VGPR).
// Per step: poll -> h A-frags direct from hglob (relaxed agent 8B atomics,
// packed hi|lo u32) -> 3-chain split MFMA onto precomputed x-partials ->
// in-lane-free cell via small LDS gate exchange -> packed h store -> barrier
// arrive -> x-phase for t+1 (cached loads: xpk planes or emb+convert) overlaps
// the barrier wait.
// ---------------------------------------------------------------------------
__global__ __launch_bounds__(256, 1) void lstm_mfma_kernel(
    const int* __restrict__ sent, const float* __restrict__ emb,
    const ushort* __restrict__ planes, const u32* __restrict__ xpk,
    const float* __restrict__ bif, const float* __restrict__ bhf,
    const float* __restrict__ bib, const float* __restrict__ bhb,
    const float* __restrict__ wout,
    const float* __restrict__ h0, const float* __restrict__ c0,
    u32* __restrict__ hglob,      // [2 par][2 dir][64 b][512] packed hi|lo
    float* __restrict__ logits,   // [512][64][7] atomicAdd
    int* __restrict__ barrier)    // [2 dir][32]
{
    __shared__ float sums_s[4 * 32 * 16];   // [gate][b][u]
    __shared__ float hv_s[32 * 16];
    __shared__ float bias_s[4 * 16];
    __shared__ float wout_s[7 * 16];
    __shared__ int   sidx_s[32];

    const int tid = threadIdx.x;
    const int w   = tid >> 6;
    const int L   = tid & 63;
    const int ln  = L & 15;
    const int lk  = L >> 4;
    const int d   = blockIdx.x & 1;
    const int ub  = blockIdx.x >> 1;
    const int bh  = ub & 1;
    const int ut  = ub >> 1;          // 0..31
    const int u0  = ut << 4;
    const int B0  = bh << 5;
    const int bs  = (w & 1) << 4;
    const int gp  = w >> 1;

    const ushort* wih_hi = planes + ((size_t)((d*2 + 0)*2 + 0)) * 1048576;
    const ushort* wih_lo = planes + ((size_t)((d*2 + 0)*2 + 1)) * 1048576;
    const ushort* whh_hi = planes + ((size_t)((d*2 + 1)*2 + 0)) * 1048576;
    const ushort* whh_lo = planes + ((size_t)((d*2 + 1)*2 + 1)) * 1048576;

    // register-resident Whh B-frags: B[k][n], n=lane&15 -> unit col, k=lk*8+j
    bf16x8 Bh[2][16], Bl[2][16];
#pragma unroll
    for (int nt = 0; nt < 2; ++nt) {
        const size_t row = (size_t)((gp*2 + nt)*512 + u0 + ln);
#pragma unroll
        for (int kb = 0; kb < 16; ++kb) {
            Bh[nt][kb] = *(const bf16x8*)(whh_hi + row*512 + kb*32 + lk*8);
            Bl[nt][kb] = *(const bf16x8*)(whh_lo + row*512 + kb*32 + lk*8);
        }
    }
    if (tid < 64) {
        int g = tid >> 4, uu = tid & 15;
        int grow = g*512 + u0 + uu;
        bias_s[tid] = d ? (bib[grow] + bhb[grow]) : (bif[grow] + bhf[grow]);
    }
    if (tid < 112) {
        int tg = tid >> 4, uu = tid & 15;
        wout_s[tid] = wout[(size_t)tg*1024 + d*512 + u0 + uu];
    }
    if (tid < 32) sidx_s[tid] = sent[(B0 + tid)*512 + (d ? 511 : 0)];

    float cst[2];
    {
        int p0 = tid << 1;
        int b = p0 >> 4, uu = p0 & 15;
        const float* cr = c0 + ((size_t)(d*64) + B0 + b)*512 + u0 + uu;
        cst[0] = cr[0]; cst[1] = cr[1];
    }
    int* cnt = barrier + d*32;
    int* rel = barrier + d*32 + 16;
    __syncthreads();

    const int bg = B0 + bs + ln;   // this lane's global batch (A-frag row)
    f32x4 xacc0a, xacc0b, xacc1a, xacc1b;

    // ---- x-phase: split-MFMA x_t . W_ih^T into xacc (runs in barrier shadow) ----
    auto x_phase = [&](int tnext) {
        f32x4 a0a = {0,0,0,0}, a0b = {0,0,0,0}, a1a = {0,0,0,0}, a1b = {0,0,0,0};
        const size_t row0 = (size_t)((gp*2 + 0)*512 + u0 + ln);
        const size_t row1 = (size_t)((gp*2 + 1)*512 + u0 + ln);
#pragma unroll
        for (int kb = 0; kb < 16; ++kb) {
            frag_u Ah, Al;
            if (xpk) {
                const u32* xp = xpk + ((size_t)bg*512 + tnext)*512 + kb*32 + lk*8;
                uint4 q0 = *(const uint4*)(xp);
                uint4 q1 = *(const uint4*)(xp + 4);
                Ah.d[0] = __builtin_amdgcn_perm(q0.y, q0.x, 0x07060302u);
                Ah.d[1] = __builtin_amdgcn_perm(q0.w, q0.z, 0x07060302u);
                Ah.d[2] = __builtin_amdgcn_perm(q1.y, q1.x, 0x07060302u);
                Ah.d[3] = __builtin_amdgcn_perm(q1.w, q1.z, 0x07060302u);
                Al.d[0] = __builtin_amdgcn_perm(q0.y, q0.x, 0x05040100u);
                Al.d[1] = __builtin_amdgcn_perm(q0.w, q0.z, 0x05040100u);
                Al.d[2] = __builtin_amdgcn_perm(q1.y, q1.x, 0x05040100u);
                Al.d[3] = __builtin_amdgcn_perm(q1.w, q1.z, 0x05040100u);
            } else {
                int tok = sidx_s[bs + ln];
                const float* xr = emb + (size_t)tok*512 + kb*32 + lk*8;
                float4 f0 = *(const float4*)(xr);
                float4 f1 = *(const float4*)(xr + 4);
                u32 ubits[8], rbits[8];
                float* ff = (float*)&f0;
#pragma unroll
                for (int j = 0; j < 4; ++j) {
                    ubits[j] = __float_as_uint(ff[j]);
                    rbits[j] = __float_as_uint(ff[j] - __uint_as_float(ubits[j] & 0xffff0000u));
                }
                ff = (float*)&f1;
#pragma unroll
                for (int j = 0; j < 4; ++j) {
                    ubits[4+j] = __float_as_uint(ff[j]);
                    rbits[4+j] = __float_as_uint(ff[j] - __uint_as_float(ubits[4+j] & 0xffff0000u));
                }
                Ah.d[0] = __builtin_amdgcn_perm(ubits[1], ubits[0], 0x07060302u);
                Ah.d[1] = __builtin_amdgcn_perm(ubits[3], ubits[2], 0x07060302u);
                Ah.d[2] = __builtin_amdgcn_perm(ubits[5], ubits[4], 0x07060302u);
                Ah.d[3] = __builtin_amdgcn_perm(ubits[7], ubits[6], 0x07060302u);
                Al.d[0] = __builtin_amdgcn_perm(rbits[1], rbits[0], 0x07060302u);
                Al.d[1] = __builtin_amdgcn_perm(rbits[3], rbits[2], 0x07060302u);
                Al.d[2] = __builtin_amdgcn_perm(rbits[5], rbits[4], 0x07060302u);
                Al.d[3] = __builtin_amdgcn_perm(rbits[7], rbits[6], 0x07060302u);
            }
            bf16x8 b0h = *(const bf16x8*)(wih_hi + row0*512 + kb*32 + lk*8);
            bf16x8 b0l = *(const bf16x8*)(wih_lo + row0*512 + kb*32 + lk*8);
            bf16x8 b1h = *(const bf16x8*)(wih_hi + row1*512 + kb*32 + lk*8);
            bf16x8 b1l = *(const bf16x8*)(wih_lo + row1*512 + kb*32 + lk*8);
            if (kb & 1) {
                a0b = MFMA(Al.v, b0h, a0b); a0b = MFMA(Ah.v, b0l, a0b); a0b = MFMA(Ah.v, b0h, a0b);
                a1b = MFMA(Al.v, b1h, a1b); a1b = MFMA(Ah.v, b1l, a1b); a1b = MFMA(Ah.v, b1h, a1b);
            } else {
                a0a = MFMA(Al.v, b0h, a0a); a0a = MFMA(Ah.v, b0l, a0a); a0a = MFMA(Ah.v, b0h, a0a);
                a1a = MFMA(Al.v, b1h, a1a); a1a = MFMA(Ah.v, b1l, a1a); a1a = MFMA(Ah.v, b1h, a1a);
            }
        }
        xacc0a = a0a; xacc0b = a0b; xacc1a = a1a; xacc1b = a1b;
    };

    x_phase(d ? 511 : 0);

    for (int s = 0; s < 512; ++s) {
        const int t = d ? (511 - s) : s;

        if (s > 0 && tid == 0) {
            while (__hip_atomic_load(rel, __ATOMIC_RELAXED, __HIP_MEMORY_SCOPE_AGENT) < s)
                __builtin_amdgcn_s_sleep(1);
        }
        __syncthreads();   // also separates prev x_phase from sidx_s rewrite

        if (s < 511 && tid < 32)
            sidx_s[tid] = sent[(B0 + tid)*512 + (d ? (510 - s) : (s + 1))];

        // ---- h-phase: split MFMA onto xacc ----
        f32x4 f0a = xacc0a, f0b = xacc0b, f1a = xacc1a, f1b = xacc1b;
        if (s == 0) {
            const float* hr = h0 + ((size_t)(d*64) + bg)*512;
#pragma unroll
            for (int kb = 0; kb < 16; ++kb) {
                float4 f0 = *(const float4*)(hr + kb*32 + lk*8);
                float4 f1 = *(const float4*)(hr + kb*32 + lk*8 + 4);
                u32 ubits[8], rbits[8];
                float* ff = (float*)&f0;
#pragma unroll
                for (int j = 0; j < 4; ++j) {
                    ubits[j] = __float_as_uint(ff[j]);
                    rbits[j] = __float_as_uint(ff[j] - __uint_as_float(ubits[j] & 0xffff0000u));
                }
                ff = (float*)&f1;
#pragma unroll
                for (int j = 0; j < 4; ++j) {
                    ubits[4+j] = __float_as_uint(ff[j]);
                    rbits[4+j] = __float_as_uint(ff[j] - __uint_as_float(ubits[4+j] & 0xffff0000u));
                }
                frag_u Ah, Al;
                Ah.d[0] = __builtin_amdgcn_perm(ubits[1], ubits[0], 0x07060302u);
                Ah.d[1] = __builtin_amdgcn_perm(ubits[3], ubits[2], 0x07060302u);
                Ah.d[2] = __builtin_amdgcn_perm(ubits[5], ubits[4], 0x07060302u);
                Ah.d[3] = __builtin_amdgcn_perm(ubits[7], ubits[6], 0x07060302u);
                Al.d[0] = __builtin_amdgcn_perm(rbits[1], rbits[0], 0x07060302u);
                Al.d[1] = __builtin_amdgcn_perm(rbits[3], rbits[2], 0x07060302u);
                Al.d[2] = __builtin_amdgcn_perm(rbits[5], rbits[4], 0x07060302u);
                Al.d[3] = __builtin_amdgcn_perm(rbits[7], rbits[6], 0x07060302u);
                if (kb & 1) {
                    f0b = MFMA(Al.v, Bh[0][kb], f0b); f0b = MFMA(Ah.v, Bl[0][kb], f0b); f0b = MFMA(Ah.v, Bh[0][kb], f0b);
                    f1b = MFMA(Al.v, Bh[1][kb], f1b); f1b = MFMA(Ah.v, Bl[1][kb], f1b); f1b = MFMA(Ah.v, Bh[1][kb], f1b);
                } else {
                    f0a = MFMA(Al.v, Bh[0][kb], f0a); f0a = MFMA(Ah.v, Bl[0][kb], f0a); f0a = MFMA(Ah.v, Bh[0][kb], f0a);
                    f1a = MFMA(Al.v, Bh[1][kb], f1a); f1a = MFMA(Ah.v, Bl[1][kb], f1a); f1a = MFMA(Ah.v, Bh[1][kb], f1a);
                }
            }
        } else {
            const u32* hbase = hglob + ((size_t)((s & 1)*2 + d)*64 + bg)*512;
#pragma unroll
            for (int kb = 0; kb < 16; ++kb) {
                const u64* hp = (const u64*)(hbase + kb*32 + lk*8);
                u64 q0 = __hip_atomic_load(hp + 0, __ATOMIC_RELAXED, __HIP_MEMORY_SCOPE_AGENT);
                u64 q1 = __hip_atomic_load(hp + 1, __ATOMIC_RELAXED, __HIP_MEMORY_SCOPE_AGENT);
                u64 q2 = __hip_atomic_load(hp + 2, __ATOMIC_RELAXED, __HIP_MEMORY_SCOPE_AGENT);
                u64 q3 = __hip_atomic_load(hp + 3, __ATOMIC_RELAXED, __HIP_MEMORY_SCOPE_AGENT);
                u32 p0 = (u32)q0, p1 = (u32)(q0 >> 32);
                u32 p2 = (u32)q1, p3 = (u32)(q1 >> 32);
                u32 p4 = (u32)q2, p5 = (u32)(q2 >> 32);
                u32 p6 = (u32)q3, p7 = (u32)(q3 >> 32);
                frag_u Ah, Al;
                Ah.d[0] = __builtin_amdgcn_perm(p1, p0, 0x07060302u);
                Ah.d[1] = __builtin_amdgcn_perm(p3, p2, 0x07060302u);
                Ah.d[2] = __builtin_amdgcn_perm(p5, p4, 0x07060302u);
                Ah.d[3] = __builtin_amdgcn_perm(p7, p6, 0x07060302u);
                Al.d[0] = __builtin_amdgcn_perm(p1, p0, 0x05040100u);
                Al.d[1] = __builtin_amdgcn_perm(p3, p2, 0x05040100u);
                Al.d[2] = __builtin_amdgcn_perm(p5, p4, 0x05040100u);
                Al.d[3] = __builtin_amdgcn_perm(p7, p6, 0x05040100u);
                if (kb & 1) {
                    f0b = MFMA(Al.v, Bh[0][kb], f0b); f0b = MFMA(Ah.v, Bl[0][kb], f0b); f0b = MFMA(Ah.v, Bh[0][kb], f0b);
                    f1b = MFMA(Al.v, Bh[1][kb], f1b); f1b = MFMA(Ah.v, Bl[1][kb], f1b); f1b = MFMA(Ah.v, Bh[1][kb], f1b);
                } else {
                    f0a = MFMA(Al.v, Bh[0][kb], f0a); f0a = MFMA(Ah.v, Bl[0][kb], f0a); f0a = MFMA(Ah.v, Bh[0][kb], f0a);
                    f1a = MFMA(Al.v, Bh[1][kb], f1a); f1a = MFMA(Ah.v, Bl[1][kb], f1a); f1a = MFMA(Ah.v, Bh[1][kb], f1a);
                }
            }
        }
        f32x4 g0 = f0a + f0b, g1 = f1a + f1b;

        // ---- write gate sums: C row = batch = lk*4+r, col = unit = ln ----
#pragma unroll
        for (int r = 0; r < 4; ++r) {
            int b = bs + lk*4 + r;
            sums_s[(((gp*2 + 0)*32 + b) << 4) + ln] = g0[r];
            sums_s[(((gp*2 + 1)*32 + b) << 4) + ln] = g1[r];
        }
        __syncthreads();

        // ---- cell update: 2 (b,u) pairs per thread, c in regs ----
        {
            int p0 = tid << 1;
            int bb = p0 >> 4, uu0 = p0 & 15;
            u32 pk[2];
#pragma unroll
            for (int e = 0; e < 2; ++e) {
                int uu = uu0 + e;
                float si = sums_s[((0*32 + bb) << 4) + uu] + bias_s[uu];
                float sf = sums_s[((1*32 + bb) << 4) + uu] + bias_s[16 + uu];
                float sg = sums_s[((2*32 + bb) << 4) + uu] + bias_s[32 + uu];
                float so = sums_s[((3*32 + bb) << 4) + uu] + bias_s[48 + uu];
                float ig = 1.f / (1.f + expf(-si));
                float fg = 1.f / (1.f + expf(-sf));
                float gv = tanhf(sg);
                float og = 1.f / (1.f + expf(-so));
                float cn = fg * cst[e] + ig * gv;
                cst[e] = cn;
                float hh = og * tanhf(cn);
                hv_s[(bb << 4) + uu] = hh;
                u32 hb = __float_as_uint(hh);
                float rr = hh - __uint_as_float(hb & 0xffff0000u);
                pk[e] = (hb & 0xffff0000u) | (__float_as_uint(rr) >> 16);
            }
            u64 pk2 = (u64)pk[0] | ((u64)pk[1] << 32);
            u64* dst = (u64*)(hglob + ((size_t)(((s + 1) & 1)*2 + d)*64 + B0 + bb)*512 + u0 + uu0);
            __hip_atomic_store(dst, pk2, __ATOMIC_RELAXED, __HIP_MEMORY_SCOPE_AGENT);
        }
        __syncthreads();

        // ---- partial tag logits for our 16 units ----
        if (tid < 224) {
            int tg = tid >> 5, b = tid & 31;
            float a = 0.f;
#pragma unroll
            for (int uu = 0; uu < 16; ++uu)
                a = fmaf(hv_s[(b << 4) + uu], wout_s[tg*16 + uu], a);
            atomicAdd(&logits[((size_t)t*64 + B0 + b)*NTAG + tg], a);
        }

        // ---- barrier arrive (h stores drained first), then overlap x ----
        __builtin_amdgcn_s_waitcnt(0);
        __syncthreads();
        if (tid == 0) {
            int old = __hip_atomic_fetch_add(cnt, 1, __ATOMIC_RELAXED, __HIP_MEMORY_SCOPE_AGENT);
            if (old == s*64 + 63)
                __hip_atomic_store(rel, s + 1, __ATOMIC_RELAXED, __HIP_MEMORY_SCOPE_AGENT);
        }
        if (s < 511) x_phase(d ? (510 - s) : (s + 1));
    }
}

// ---------------------------------------------------------------------------
// Viterbi decode: one wave per batch (lanes 0..6 = tags), byte backpointers.
// ---------------------------------------------------------------------------
__global__ __launch_bounds__(256) void viterbi_kernel(
    const float* __restrict__ logits, const float* __restrict__ bout,
    const float* __restrict__ trans,
    unsigned char* __restrict__ bp,   // [64][512][8]
    float* __restrict__ out)          // [64 scores][64*512 paths]
{
    __shared__ float Ls[4][512][7];
    const int tid = threadIdx.x;
    const int b0 = blockIdx.x << 2;

    for (int idx = tid; idx < 4*512*7; idx += 256) {
        int bl = idx / 3584;
        int rem = idx - bl*3584;
        int t = rem / 7;
        int tg = rem - t*7;
        Ls[bl][t][tg] = logits[((size_t)t*64 + b0 + bl)*7 + tg] + bout[tg];
    }
    __syncthreads();

    const int w = tid >> 6;
    const int lane = tid & 63;
    const int b = b0 + w;
    const int k = lane;

    float tr[7];
#pragma unroll
    for (int j = 0; j < 7; ++j) tr[j] = (k < 7) ? trans[j*7 + k] : -1e30f;
    float prev = (k < 7) ? Ls[w][0][k] : -1e30f;
    unsigned char* bpb = bp + (size_t)b*512*8;

    for (int t = 1; t < 512; ++t) {
        float best = __shfl(prev, 0, 64) + tr[0];
        int bj = 0;
#pragma unroll
        for (int j = 1; j < 7; ++j) {
            float v = __shfl(prev, j, 64) + tr[j];
            if (v > best) { best = v; bj = j; }
        }
        float lv = (k < 7) ? Ls[w][t][k] : 0.f;
        if (k < 7) bpb[t*8 + k] = (unsigned char)bj;
        prev = lv + best;
    }

    float pv[7];
#pragma unroll
    for (int j = 0; j < 7; ++j) pv[j] = __shfl(prev, j, 64);
    float best = pv[0]; int bj = 0;
#pragma unroll
    for (int j = 1; j < 7; ++j) if (pv[j] > best) { best = pv[j]; bj = j; }
    if (lane == 0) {
        out[b] = best;
        out[64 + (size_t)b*512 + 511] = (float)bj;
    }

    int cur = bj;
    for (int tc = 448; tc >= 0; tc -= 64) {
        int t = tc + lane;
        u64 row = *(const u64*)(bpb + (size_t)t*8);
        for (int i = 63; i >= 0; --i) {
            int t2 = tc + i;
            if (t2 < 1) break;
            u64 r = __shfl(row, i, 64);
            cur = (int)((r >> (cur*8)) & 0xFF);
            if (lane == 0) out[64 + (size_t)b*512 + (t2 - 1)] = (float)cur;
        }
    }
}

// ---------------------------------------------------------------------------
extern "C" void kernel_launch(void* const* d_in, const int* in_sizes, int n_in,
                              void* d_out, int out_size, void* d_ws, size_t ws_size,
                              hipStream_t stream)
{
    (void)in_sizes; (void)n_in; (void)out_size;
    const int*   sent = (const int*)d_in[0];
    const float* emb  = (const float*)d_in[1];
    const float* wif  = (const float*)d_in[2];
    const float* whf  = (const float*)d_in[3];
    const float* bif  = (const float*)d_in[4];
    const float* bhf  = (const float*)d_in[5];
    const float* wib  = (const float*)d_in[6];
    const float* whb  = (const float*)d_in[7];
    const float* bib  = (const float*)d_in[8];
    const float* bhb  = (const float*)d_in[9];
    const float* wout = (const float*)d_in[10];
    const float* bout = (const float*)d_in[11];
    const float* h0   = (const float*)d_in[12];
    const float* c0   = (const float*)d_in[13];
    const float* trans= (const float*)d_in[14];
    float* out = (float*)d_out;

    // ws layout: barrier(1KB) | logits(917504) | hglob(524288) | planes(16MB) | bp | [xpk 64MB]
    char* p = (char*)d_ws;
    int*    barrier = (int*)p;                 p += 1024;
    float*  logits  = (float*)p;               p += 917504;
    u32*    hglob   = (u32*)p;                 p += 524288;
    ushort* planes  = (ushort*)p;              p += 16777216;
    unsigned char* bp = (unsigned char*)p;     p += 262144;
    size_t base_need = (size_t)(p - (char*)d_ws);
    u32* xpk = nullptr;
    if (ws_size >= base_need + (size_t)67108864) xpk = (u32*)p;

    hipMemsetAsync(d_ws, 0, 1024 + 917504, stream);   // barrier + logits
    prep_weights_kernel<<<4096, 256, 0, stream>>>(wif, whf, wib, whb, planes);
    if (xpk) prep_x_kernel<<<16384, 256, 0, stream>>>(sent, emb, xpk);
    lstm_mfma_kernel<<<128, 256, 0, stream>>>(
        sent, emb, planes, xpk, bif, bhf, bib, bhb,
        wout, h0, c0, hglob, logits, barrier);
    viterbi_kernel<<<16, 256, 0, stream>>>(logits, bout, trans, bp, out);
}

// Round 5
// 6838.200 us; speedup vs baseline: 4.5225x; 1.8124x over previous
//
#include <hip/hip_runtime.h>
#include <cstdint>
#include <cstddef>

#define NTAG 7

typedef unsigned int u32;
typedef unsigned long long u64;
using bf16x8 = __attribute__((ext_vector_type(8))) short;
using f32x4  = __attribute__((ext_vector_type(4))) float;

#define MFMA(A,B,C) __builtin_amdgcn_mfma_f32_16x16x32_bf16((A),(B),(C),0,0,0)

union abf { u64 q[2]; ushort e[8]; bf16x8 v; };

__device__ __forceinline__ u32 rtn_bf16(float f) {   // round-to-nearest-even
    u32 b = __float_as_uint(f);
    return (b + 0x7fffu + ((b >> 16) & 1u)) >> 16;
}

// ---------------------------------------------------------------------------
// Prep 1: fp32 -> bf16 (RTN) weight planes. order: 0=wif 1=whf 2=wib 3=whb
// ---------------------------------------------------------------------------
__global__ __launch_bounds__(256) void prep_w_kernel(
    const float* __restrict__ wif, const float* __restrict__ whf,
    const float* __restrict__ wib, const float* __restrict__ whb,
    ushort* __restrict__ planes)
{
    int f = blockIdx.x * 256 + threadIdx.x;          // x8 elems
    int mat = f >> 17;
    int i8 = (f & 0x1FFFF) << 3;
    const float* src = (mat == 0) ? wif : (mat == 1) ? whf : (mat == 2) ? wib : whb;
    float4 v0 = *(const float4*)(src + i8);
    float4 v1 = *(const float4*)(src + i8 + 4);
    ushort o[8];
    const float* pv = (const float*)&v0;
#pragma unroll
    for (int j = 0; j < 4; ++j) o[j] = (ushort)rtn_bf16(pv[j]);
    pv = (const float*)&v1;
#pragma unroll
    for (int j = 0; j < 4; ++j) o[4 + j] = (ushort)rtn_bf16(pv[j]);
    ushort* dst = planes + ((size_t)mat << 20) + i8;
    *(ushort4*)dst = make_ushort4(o[0], o[1], o[2], o[3]);
    *(ushort4*)(dst + 4) = make_ushort4(o[4], o[5], o[6], o[7]);
}

// ---------------------------------------------------------------------------
// Prep 2 (optional): xb[b][t][e] = bf16(emb[sent[b][t]][e])
// ---------------------------------------------------------------------------
__global__ __launch_bounds__(256) void prep_x_kernel(
    const int* __restrict__ sent, const float* __restrict__ emb,
    ushort* __restrict__ xb)
{
    long f = (long)blockIdx.x * 256 + threadIdx.x;   // x8 elems
    long e8 = f << 3;
    int bt = (int)(e8 >> 9);
    int e  = (int)(e8 & 511);
    int tok = sent[bt];
    const float* src = emb + (size_t)tok * 512 + e;
    float4 v0 = *(const float4*)(src);
    float4 v1 = *(const float4*)(src + 4);
    ushort o[8];
    const float* pv = (const float*)&v0;
#pragma unroll
    for (int j = 0; j < 4; ++j) o[j] = (ushort)rtn_bf16(pv[j]);
    pv = (const float*)&v1;
#pragma unroll
    for (int j = 0; j < 4; ++j) o[4 + j] = (ushort)rtn_bf16(pv[j]);
    ushort* dst = xb + e8;
    *(ushort4*)dst = make_ushort4(o[0], o[1], o[2], o[3]);
    *(ushort4*)(dst + 4) = make_ushort4(o[4], o[5], o[6], o[7]);
}

// ---------------------------------------------------------------------------
// Main persistent kernel: 128 blocks x 256 thr (4 waves), 1 block/CU.
// group g = blockIdx&7 = (dir d, batch-quarter bq: 16 batches); slot =
// blockIdx>>3 -> 32 units. wave w = gate w, 2 n-tiles of 16 units.
// W_hh bf16 B-frags register-resident (128 VGPR). h exchanged as bf16 via
// relaxed agent atomics; 16-block flag barrier (parallel stores, no RMW).
// x-phase for t+1 runs after the flag store, inside the barrier shadow.
// ---------------------------------------------------------------------------
__global__ __launch_bounds__(256, 1) void lstm_mfma_kernel(
    const int* __restrict__ sent, const float* __restrict__ emb,
    const ushort* __restrict__ planes, const ushort* __restrict__ xb,
    const float* __restrict__ bif, const float* __restrict__ bhf,
    const float* __restrict__ bib, const float* __restrict__ bhb,
    const float* __restrict__ wout,
    const float* __restrict__ h0, const float* __restrict__ c0,
    ushort* __restrict__ hglob,   // [2 par][2 d][64 b][512] bf16
    float* __restrict__ logits,   // [512][64][7] atomicAdd
    int* __restrict__ flags)      // [8 g][16 slot][16 pad]
{
    __shared__ float sums_s[4 * 16 * 33];   // [gate][b][33]
    __shared__ float hv_s[16 * 33];
    __shared__ float bias_s[4 * 32];
    __shared__ float wout_s[7 * 33];

    const int tid = threadIdx.x;
    const int w   = tid >> 6;       // wave = gate
    const int L   = tid & 63;
    const int ln  = L & 15;
    const int lk  = L >> 4;
    const int g   = blockIdx.x & 7;
    const int slot= blockIdx.x >> 3;
    const int d   = g & 1;
    const int bq  = g >> 1;
    const int B0  = bq << 4;
    const int u0  = slot << 5;

    const ushort* wip = planes + ((size_t)(d ? 2 : 0) << 20);
    const ushort* whp = planes + ((size_t)(d ? 3 : 1) << 20);

    // register-resident W_hh B-frags: rows = gate w, units u0 + h*16 + ln
    bf16x8 Bh[2][16];
#pragma unroll
    for (int h = 0; h < 2; ++h) {
        const size_t row = (size_t)(w * 512 + u0 + h * 16 + ln);
#pragma unroll
        for (int kb = 0; kb < 16; ++kb)
            Bh[h][kb] = *(const bf16x8*)(whp + row * 512 + kb * 32 + lk * 8);
    }
    if (tid < 128) {
        int gg = tid >> 5, uu = tid & 31;
        int grow = gg * 512 + u0 + uu;
        bias_s[tid] = d ? (bib[grow] + bhb[grow]) : (bif[grow] + bhf[grow]);
    }
    if (tid < 224) {
        int tg = tid >> 5, uu = tid & 31;
        wout_s[tg * 33 + uu] = wout[(size_t)tg * 1024 + d * 512 + u0 + uu];
    }
    // c-state: thread -> (b = tid>>4, units uh*2, uh*2+1)
    const int cb = tid >> 4, uh = tid & 15;
    float cst[2];
    {
        const float* cr = c0 + ((size_t)(d * 64) + B0 + cb) * 512 + u0 + uh * 2;
        cst[0] = cr[0]; cst[1] = cr[1];
    }
    __syncthreads();

    const int gb = B0 + ln;                 // this lane's global batch
    f32x4 xacc0, xacc1;

    // x-phase: split into barrier shadow; accumulates x_t . W_ih^T
    auto x_phase = [&](int tnext) {
        f32x4 a0a = {0,0,0,0}, a0b = {0,0,0,0}, a1a = {0,0,0,0}, a1b = {0,0,0,0};
        const size_t row0 = (size_t)(w * 512 + u0 + ln);
        const size_t row1 = row0 + 16;
#pragma unroll
        for (int kb = 0; kb < 16; ++kb) {
            bf16x8 A;
            if (xb) {
                A = *(const bf16x8*)(xb + ((size_t)gb * 512 + tnext) * 512 + kb * 32 + lk * 8);
            } else {
                int tok = sent[gb * 512 + tnext];
                const float* xr = emb + (size_t)tok * 512 + kb * 32 + lk * 8;
                float4 f0 = *(const float4*)(xr);
                float4 f1 = *(const float4*)(xr + 4);
                abf t;
                const float* pv = (const float*)&f0;
#pragma unroll
                for (int j = 0; j < 4; ++j) t.e[j] = (ushort)rtn_bf16(pv[j]);
                pv = (const float*)&f1;
#pragma unroll
                for (int j = 0; j < 4; ++j) t.e[4 + j] = (ushort)rtn_bf16(pv[j]);
                A = t.v;
            }
            bf16x8 Bx0 = *(const bf16x8*)(wip + row0 * 512 + kb * 32 + lk * 8);
            bf16x8 Bx1 = *(const bf16x8*)(wip + row1 * 512 + kb * 32 + lk * 8);
            if (kb & 1) { a0b = MFMA(A, Bx0, a0b); a1b = MFMA(A, Bx1, a1b); }
            else        { a0a = MFMA(A, Bx0, a0a); a1a = MFMA(A, Bx1, a1a); }
        }
        xacc0 = a0a + a0b;
        xacc1 = a1a + a1b;
    };

    x_phase(d ? 511 : 0);

    for (int s = 0; s < 512; ++s) {
        const int t = d ? (511 - s) : s;

        // ---- wait for all 16 producer blocks of this group (flag array) ----
        if (s > 0 && w == 0) {
            const int* fp = flags + (((g << 4) + (L & 15)) << 4);
            while (true) {
                int v = __hip_atomic_load(fp, __ATOMIC_RELAXED, __HIP_MEMORY_SCOPE_AGENT);
                if (__all(v >= s)) break;
                __builtin_amdgcn_s_sleep(1);
            }
        }
        __syncthreads();

        // ---- h-phase MFMA onto x partials ----
        f32x4 f0a = xacc0, f0b = {0,0,0,0}, f1a = xacc1, f1b = {0,0,0,0};
        if (s == 0) {
            const float* hr = h0 + ((size_t)(d * 64) + gb) * 512;
#pragma unroll
            for (int kb = 0; kb < 16; ++kb) {
                float4 q0 = *(const float4*)(hr + kb * 32 + lk * 8);
                float4 q1 = *(const float4*)(hr + kb * 32 + lk * 8 + 4);
                abf A;
                const float* pv = (const float*)&q0;
#pragma unroll
                for (int j = 0; j < 4; ++j) A.e[j] = (ushort)rtn_bf16(pv[j]);
                pv = (const float*)&q1;
#pragma unroll
                for (int j = 0; j < 4; ++j) A.e[4 + j] = (ushort)rtn_bf16(pv[j]);
                if (kb & 1) { f0b = MFMA(A.v, Bh[0][kb], f0b); f1b = MFMA(A.v, Bh[1][kb], f1b); }
                else        { f0a = MFMA(A.v, Bh[0][kb], f0a); f1a = MFMA(A.v, Bh[1][kb], f1a); }
            }
        } else {
            const ushort* hbase = hglob + ((size_t)((s & 1) * 2 + d) * 64 + gb) * 512;
#pragma unroll
            for (int kb = 0; kb < 16; ++kb) {
                const u64* hp = (const u64*)(hbase + kb * 32 + lk * 8);
                abf A;
                A.q[0] = __hip_atomic_load(hp + 0, __ATOMIC_RELAXED, __HIP_MEMORY_SCOPE_AGENT);
                A.q[1] = __hip_atomic_load(hp + 1, __ATOMIC_RELAXED, __HIP_MEMORY_SCOPE_AGENT);
                if (kb & 1) { f0b = MFMA(A.v, Bh[0][kb], f0b); f1b = MFMA(A.v, Bh[1][kb], f1b); }
                else        { f0a = MFMA(A.v, Bh[0][kb], f0a); f1a = MFMA(A.v, Bh[1][kb], f1a); }
            }
        }
        f32x4 g0 = f0a + f0b, g1 = f1a + f1b;

        // ---- gate sums -> LDS: C row = batch lk*4+r, col = unit ----
#pragma unroll
        for (int r = 0; r < 4; ++r) {
            int b = lk * 4 + r;
            sums_s[w * 528 + b * 33 + ln]      = g0[r];
            sums_s[w * 528 + b * 33 + 16 + ln] = g1[r];
        }
        __syncthreads();

        // ---- cell update: all 256 threads, 2 (b,u) pairs ----
        {
            u32 pk = 0;
#pragma unroll
            for (int e = 0; e < 2; ++e) {
                int u = uh * 2 + e;
                float si = sums_s[0 * 528 + cb * 33 + u] + bias_s[u];
                float sf = sums_s[1 * 528 + cb * 33 + u] + bias_s[32 + u];
                float sg = sums_s[2 * 528 + cb * 33 + u] + bias_s[64 + u];
                float so = sums_s[3 * 528 + cb * 33 + u] + bias_s[96 + u];
                float ig = 1.f / (1.f + expf(-si));
                float fg = 1.f / (1.f + expf(-sf));
                float gv = tanhf(sg);
                float og = 1.f / (1.f + expf(-so));
                float cn = fg * cst[e] + ig * gv;
                cst[e] = cn;
                float hh = og * tanhf(cn);
                hv_s[cb * 33 + u] = hh;
                pk |= rtn_bf16(hh) << (16 * e);
            }
            u32* dst = (u32*)(hglob + ((size_t)(((s + 1) & 1) * 2 + d) * 64 + B0 + cb) * 512 + u0 + uh * 2);
            __hip_atomic_store(dst, pk, __ATOMIC_RELAXED, __HIP_MEMORY_SCOPE_AGENT);
        }
        __syncthreads();

        // ---- partial tag logits (this block's 32 units) ----
        if (tid < 112) {
            int tg = tid >> 4, b = tid & 15;
            float a = 0.f;
#pragma unroll
            for (int u = 0; u < 32; ++u)
                a = fmaf(hv_s[b * 33 + u], wout_s[tg * 33 + u], a);
            atomicAdd(&logits[((size_t)t * 64 + B0 + b) * NTAG + tg], a);
        }

        // ---- drain h stores, arrive (parallel flag store), overlap x ----
        __builtin_amdgcn_s_waitcnt(0);
        __syncthreads();
        if (tid == 0)
            __hip_atomic_store(flags + (((g << 4) + slot) << 4), s + 1,
                               __ATOMIC_RELAXED, __HIP_MEMORY_SCOPE_AGENT);
        if (s < 511) x_phase(d ? (510 - s) : (s + 1));
    }
}

// ---------------------------------------------------------------------------
// Viterbi decode: one wave per batch (lanes 0..6 = tags), byte backpointers.
// ---------------------------------------------------------------------------
__global__ __launch_bounds__(256) void viterbi_kernel(
    const float* __restrict__ logits, const float* __restrict__ bout,
    const float* __restrict__ trans,
    unsigned char* __restrict__ bp,   // [64][512][8]
    float* __restrict__ out)          // [64 scores][64*512 paths]
{
    __shared__ float Ls[4][512][7];
    const int tid = threadIdx.x;
    const int b0 = blockIdx.x << 2;

    for (int idx = tid; idx < 4 * 512 * 7; idx += 256) {
        int bl = idx / 3584;
        int rem = idx - bl * 3584;
        int t = rem / 7;
        int tg = rem - t * 7;
        Ls[bl][t][tg] = logits[((size_t)t * 64 + b0 + bl) * 7 + tg] + bout[tg];
    }
    __syncthreads();

    const int w = tid >> 6;
    const int lane = tid & 63;
    const int b = b0 + w;
    const int k = lane;

    float tr[7];
#pragma unroll
    for (int j = 0; j < 7; ++j) tr[j] = (k < 7) ? trans[j * 7 + k] : -1e30f;
    float prev = (k < 7) ? Ls[w][0][k] : -1e30f;
    unsigned char* bpb = bp + (size_t)b * 512 * 8;

    for (int t = 1; t < 512; ++t) {
        float best = __shfl(prev, 0, 64) + tr[0];
        int bj = 0;
#pragma unroll
        for (int j = 1; j < 7; ++j) {
            float v = __shfl(prev, j, 64) + tr[j];
            if (v > best) { best = v; bj = j; }   // strict > = first argmax
        }
        float lv = (k < 7) ? Ls[w][t][k] : 0.f;
        if (k < 7) bpb[t * 8 + k] = (unsigned char)bj;
        prev = lv + best;
    }

    float pv[7];
#pragma unroll
    for (int j = 0; j < 7; ++j) pv[j] = __shfl(prev, j, 64);
    float best = pv[0]; int bj = 0;
#pragma unroll
    for (int j = 1; j < 7; ++j) if (pv[j] > best) { best = pv[j]; bj = j; }
    if (lane == 0) {
        out[b] = best;
        out[64 + (size_t)b * 512 + 511] = (float)bj;
    }

    int cur = bj;
    for (int tc = 448; tc >= 0; tc -= 64) {
        int t = tc + lane;
        u64 row = *(const u64*)(bpb + (size_t)t * 8);
        for (int i = 63; i >= 0; --i) {
            int t2 = tc + i;
            if (t2 < 1) break;
            u64 r = __shfl(row, i, 64);
            cur = (int)((r >> (cur * 8)) & 0xFF);
            if (lane == 0) out[64 + (size_t)b * 512 + (t2 - 1)] = (float)cur;
        }
    }
}

// ---------------------------------------------------------------------------
extern "C" void kernel_launch(void* const* d_in, const int* in_sizes, int n_in,
                              void* d_out, int out_size, void* d_ws, size_t ws_size,
                              hipStream_t stream)
{
    (void)in_sizes; (void)n_in; (void)out_size;
    const int*   sent = (const int*)d_in[0];
    const float* emb  = (const float*)d_in[1];
    const float* wif  = (const float*)d_in[2];
    const float* whf  = (const float*)d_in[3];
    const float* bif  = (const float*)d_in[4];
    const float* bhf  = (const float*)d_in[5];
    const float* wib  = (const float*)d_in[6];
    const float* whb  = (const float*)d_in[7];
    const float* bib  = (const float*)d_in[8];
    const float* bhb  = (const float*)d_in[9];
    const float* wout = (const float*)d_in[10];
    const float* bout = (const float*)d_in[11];
    const float* h0   = (const float*)d_in[12];
    const float* c0   = (const float*)d_in[13];
    const float* trans= (const float*)d_in[14];
    float* out = (float*)d_out;

    // ws: logits(917504) | flags(8192) | hglob(256K ushort=512K... 262144B)
    //     | bp(262144) | planes(8MB) | xb(32MB optional)
    char* p = (char*)d_ws;
    float*  logits = (float*)p;            p += 917504;
    int*    flags  = (int*)p;              p += 8192;
    ushort* hglob  = (ushort*)p;           p += 2 * 2 * 64 * 512 * 2;   // 262144
    unsigned char* bp = (unsigned char*)p; p += 262144;
    ushort* planes = (ushort*)p;           p += 4 * 1048576 * 2;        // 8 MB
    size_t base_need = (size_t)(p - (char*)d_ws);
    ushort* xb = nullptr;
    if (ws_size >= base_need + (size_t)64 * 512 * 512 * 2) xb = (ushort*)p;

    hipMemsetAsync(d_ws, 0, 917504 + 8192, stream);   // logits + flags
    prep_w_kernel<<<2048, 256, 0, stream>>>(wif, whf, wib, whb, planes);
    if (xb) prep_x_kernel<<<8192, 256, 0, stream>>>(sent, emb, xb);
    lstm_mfma_kernel<<<128, 256, 0, stream>>>(
        sent, emb, planes, xb, bif, bhf, bib, bhb,
        wout, h0, c0, hglob, logits, flags);
    viterbi_kernel<<<16, 256, 0, stream>>>(logits, bout, trans, bp, out);
}